// Round 6
// baseline (135.190 us; speedup 1.0000x reference)
//
#include <hip/hip_runtime.h>
#include <hip/hip_bf16.h>

// C[1024,16384] = l2norm_rows(inputs[1024,2048]) @ features[16384,2048]^T / 0.05
// Round 6: eliminate the bconv pass. B (fp32) is reg-staged inside the GEMM:
// global_load fp32 -> f2bf -> swizzled ds_write (T14 issue-early/write-late).
// A stays bf16-preconverted (anorm) + global_load_lds. MFMA core identical to
// the verified round-5 kernel (same LDS layout/swizzle/read/epilogue).

typedef short bf16x8 __attribute__((ext_vector_type(8)));
typedef float f32x4  __attribute__((ext_vector_type(4)));

#define D_K   2048
#define N_N   16384
#define M_M   1024
#define TEMP_INV 20.0f

__device__ __forceinline__ unsigned short f2bf(float f) {
    unsigned u = __builtin_bit_cast(unsigned, f);
    u += 0x7FFFu + ((u >> 16) & 1u);   // round-to-nearest-even (finite data)
    return (unsigned short)(u >> 16);
}

#define GLOAD16(g, l) __builtin_amdgcn_global_load_lds(                        \
    (const __attribute__((address_space(1))) unsigned int*)(g),                \
    (__attribute__((address_space(3))) unsigned int*)(l), 16, 0, 0)

// ---------------- pass 1: row-norm + convert A -> bf16 --------------------
__global__ __launch_bounds__(256) void anorm_kernel(const float* __restrict__ x,
                                                    unsigned short* __restrict__ abf) {
    int row = blockIdx.x;
    int t = threadIdx.x;
    const float4* xr = reinterpret_cast<const float4*>(x + (size_t)row * D_K);
    float4 a = xr[t * 2];
    float4 b = xr[t * 2 + 1];
    float s = a.x*a.x + a.y*a.y + a.z*a.z + a.w*a.w
            + b.x*b.x + b.y*b.y + b.z*b.z + b.w*b.w;
    #pragma unroll
    for (int off = 32; off > 0; off >>= 1) s += __shfl_down(s, off);
    __shared__ float ps[4];
    __shared__ float sbc;
    if ((t & 63) == 0) ps[t >> 6] = s;
    __syncthreads();
    if (t == 0) {
        float tot = ps[0] + ps[1] + ps[2] + ps[3];
        sbc = 1.0f / fmaxf(sqrtf(tot), 1e-12f);
    }
    __syncthreads();
    float rs = sbc;
    bf16x8 v;
    v[0] = (short)f2bf(a.x * rs); v[1] = (short)f2bf(a.y * rs);
    v[2] = (short)f2bf(a.z * rs); v[3] = (short)f2bf(a.w * rs);
    v[4] = (short)f2bf(b.x * rs); v[5] = (short)f2bf(b.y * rs);
    v[6] = (short)f2bf(b.z * rs); v[7] = (short)f2bf(b.w * rs);
    *reinterpret_cast<bf16x8*>(abf + (size_t)row * D_K + t * 8) = v;
}

// ---------------- pass 2: 256x256 8-phase GEMM, fused B conversion --------
// 512 threads = 8 waves (2M x 4N). LDS 128 KiB = buf[2] x {A 32K, B 32K};
// region (mat, s) = 256 rows x 32 cols bf16 = 16 KB.
// VMEM ops per K-tile T: P1: 8 B-fp32 loads(T+2) -> regs; P2: 2 A-gl k1(T+1);
// P3: 2 A-gl k0(T+2); P4: vmcnt(4) + cvt + swizzled ds_write B(T+2).
// vmcnt(12) at P2 end guarantees A-k1(T); vmcnt(4) at P4 guarantees B8(T+2)
// and A-k0(T+1). WAR: every stage targets a region >=1 barrier after its
// last read (A-k1: read P3/P4, staged next-tile P2; A-k0: read P1/P2, staged
// P3; B: read P1/P3, written P4).
__global__ __launch_bounds__(512, 2) void gemm8f_kernel(const unsigned short* __restrict__ Abf,
                                                        const float* __restrict__ Bm,
                                                        float* __restrict__ C) {
    __shared__ __align__(16) unsigned short lds[65536];   // 128 KiB

    // 256 wgs = 4 Mtiles x 64 Ntiles; bijective XCD swizzle (256 % 8 == 0).
    // Fixed tn panel's 4 tm-readers are wg-consecutive -> same XCD (L2 share).
    int bid = blockIdx.x;
    int wg  = (bid & 7) * 32 + (bid >> 3);
    int tm  = wg & 3, tn = wg >> 2;
    int m_blk = tm * 256, n_blk = tn * 256;

    int t = threadIdx.x, lane = t & 63, w = t >> 6;
    int wm = w >> 2, wn = w & 3;                     // 2 x 4 wave grid

    // ds_read lane constants: slot = chunk ^ ((row>>1)&3)
    int l15  = lane & 15;
    int slot = ((lane >> 4) ^ ((l15 >> 1) & 3)) * 16;     // byte slot offset
    int aoff = (wm * 128 + l15) * 64 + slot;              // A region byte off
    int boff = (wn * 64  + l15) * 64 + slot;              // B region byte off

    // A stage source (pre-swizzled global chunk, rule #21), dest linear
    const unsigned short* gA[2];
    int sdst[2];
    #pragma unroll
    for (int pass = 0; pass < 2; ++pass) {
        int r = pass * 128 + (t >> 2);
        int csrc = (t & 3) ^ ((r >> 1) & 3);
        gA[pass] = Abf + (size_t)(m_blk + r) * D_K + csrc * 8;
        sdst[pass] = pass * 8192 + w * 1024;   // wave-uniform LDS dest base
    }
    auto stageA = [&](int s, int b, int ktile) {
        int kt = ktile < 32 ? ktile : 31;              // tail clamp (dead regions)
        int koff = kt * 64 + s * 32;
        int ldsb = b * 65536 + s * 16384;
        GLOAD16(gA[0] + koff, (char*)lds + ldsb + sdst[0]);
        GLOAD16(gA[1] + koff, (char*)lds + ldsb + sdst[1]);
    };

    // B reg-staging: thread t owns (row = t>>1, k-half = t&1) = 32 fp32/K-tile
    int brow = t >> 1, bhalf = t & 1;
    const float* gBsrc = Bm + (size_t)(n_blk + brow) * D_K + bhalf * 32;
    unsigned wbase = (unsigned)(32768 + bhalf * 16384 + brow * 64); // B area off
    int wsw = (brow >> 1) & 3;                         // write-side XOR swizzle
    float4 rB[8];
    auto loadB = [&](int ktile) {                      // issue-early (T14)
        int kt = ktile < 32 ? ktile : 31;
        const float4* p = reinterpret_cast<const float4*>(gBsrc + kt * 64);
        #pragma unroll
        for (int g = 0; g < 8; ++g) rB[g] = p[g];
    };
    auto writeB = [&](int b) {                         // write-late (T14)
        char* dst = (char*)lds + b * 65536 + wbase;
        #pragma unroll
        for (int g = 0; g < 4; ++g) {
            float4 x = rB[g * 2], y = rB[g * 2 + 1];
            bf16x8 v;
            v[0] = (short)f2bf(x.x); v[1] = (short)f2bf(x.y);
            v[2] = (short)f2bf(x.z); v[3] = (short)f2bf(x.w);
            v[4] = (short)f2bf(y.x); v[5] = (short)f2bf(y.y);
            v[6] = (short)f2bf(y.z); v[7] = (short)f2bf(y.w);
            *reinterpret_cast<bf16x8*>(dst + ((g ^ wsw) * 16)) = v;
        }
    };
    auto vm12 = [&] { asm volatile("s_waitcnt vmcnt(12)" ::: "memory"); };
    auto p4w  = [&](int b) {
        asm volatile("s_waitcnt vmcnt(4)" ::: "memory");
        writeB(b);
    };

    f32x4 acc[8][4] = {};
    bf16x8 bfr[4];                                     // persists across phase pairs

#define PHASE(b, mh, s, LOADB, PRE, POST)                                      \
    {                                                                          \
        bf16x8 af[4];                                                          \
        _Pragma("unroll")                                                      \
        for (int f = 0; f < 4; ++f)                                            \
            af[f] = *reinterpret_cast<const bf16x8*>(                          \
                (char*)lds + (b) * 65536 + (s) * 16384 + aoff +                \
                ((mh) * 64 + f * 16) * 64);                                    \
        if (LOADB) {                                                           \
            _Pragma("unroll")                                                  \
            for (int n = 0; n < 4; ++n)                                        \
                bfr[n] = *reinterpret_cast<const bf16x8*>(                     \
                    (char*)lds + (b) * 65536 + 32768 + (s) * 16384 + boff +    \
                    n * 1024);                                                 \
        }                                                                      \
        PRE;                                                                   \
        asm volatile("s_barrier" ::: "memory");                                \
        asm volatile("s_waitcnt lgkmcnt(0)" ::: "memory");                     \
        __builtin_amdgcn_sched_barrier(0);                                     \
        __builtin_amdgcn_s_setprio(1);                                         \
        _Pragma("unroll")                                                      \
        for (int f = 0; f < 4; ++f) {                                          \
            _Pragma("unroll")                                                  \
            for (int n = 0; n < 4; ++n)                                        \
                acc[(mh) * 4 + f][n] = __builtin_amdgcn_mfma_f32_16x16x32_bf16(\
                    af[f], bfr[n], acc[(mh) * 4 + f][n], 0, 0, 0);             \
        }                                                                      \
        __builtin_amdgcn_s_setprio(0);                                         \
        POST;                                                                  \
        asm volatile("s_barrier" ::: "memory");                                \
    }

    // prologue: B(0),B(1) loaded+written serially (compiler waits on rB deps);
    // A-k0(0), A-k1(0), A-k0(1) staged; vmcnt(4) leaves exactly
    // [A-k1(0), A-k0(1)] in flight = steady-state entry condition.
    loadB(0);
    writeB(0);
    loadB(1);
    writeB(1);
    stageA(0, 0, 0);
    stageA(1, 0, 0);
    stageA(0, 1, 1);
    asm volatile("s_waitcnt vmcnt(4)" ::: "memory");
    asm volatile("s_waitcnt lgkmcnt(0)" ::: "memory");
    asm volatile("s_barrier" ::: "memory");

    for (int u = 0; u < 16; ++u) {
        // K-tile 2u (buf0)
        PHASE(0, 0, 0, true,  (loadB(2 * u + 2)),      (void)0)
        PHASE(0, 1, 0, false, (stageA(1, 1, 2 * u + 1)), (vm12()))
        PHASE(0, 0, 1, true,  (stageA(0, 0, 2 * u + 2)), (void)0)
        PHASE(0, 1, 1, false, (void)0,                 (p4w(0)))
        // K-tile 2u+1 (buf1)
        PHASE(1, 0, 0, true,  (loadB(2 * u + 3)),      (void)0)
        PHASE(1, 1, 0, false, (stageA(1, 0, 2 * u + 2)), (vm12()))
        PHASE(1, 0, 1, true,  (stageA(0, 1, 2 * u + 3)), (void)0)
        PHASE(1, 1, 1, false, (void)0,                 (p4w(1)))
    }
#undef PHASE

    // epilogue: C/D layout col=lane&15, row=(lane>>4)*4+j [m89-verified]
    #pragma unroll
    for (int f = 0; f < 8; ++f) {
        int r = m_blk + wm * 128 + (f >> 2) * 64 + (f & 3) * 16 + (lane >> 4) * 4;
        #pragma unroll
        for (int j = 0; j < 4; ++j) {
            float* cp = C + (size_t)(r + j) * N_N + n_blk + wn * 64 + (lane & 15);
            #pragma unroll
            for (int n = 0; n < 4; ++n)
                cp[n * 16] = acc[f][n][j] * TEMP_INV;
        }
    }
}

// ================= fallback (round-1 fused fp32-staged kernel) ============
__global__ __launch_bounds__(256) void rnorm_kernel(const float* __restrict__ x,
                                                    float* __restrict__ rn) {
    int row = blockIdx.x;
    const float4* xr = reinterpret_cast<const float4*>(x + (size_t)row * D_K);
    int t = threadIdx.x;
    float4 a = xr[t];
    float4 b = xr[t + 256];
    float s = a.x*a.x + a.y*a.y + a.z*a.z + a.w*a.w
            + b.x*b.x + b.y*b.y + b.z*b.z + b.w*b.w;
    #pragma unroll
    for (int off = 32; off > 0; off >>= 1) s += __shfl_down(s, off);
    __shared__ float ps[4];
    int wave = t >> 6, lane = t & 63;
    if (lane == 0) ps[wave] = s;
    __syncthreads();
    if (t == 0) {
        float tot = ps[0] + ps[1] + ps[2] + ps[3];
        rn[row] = 1.0f / fmaxf(sqrtf(tot), 1e-12f);
    }
}

__global__ __launch_bounds__(256, 2) void gemm_kernel(const float* __restrict__ A,
                                                      const float* __restrict__ Bm,
                                                      const float* __restrict__ rn,
                                                      float* __restrict__ C) {
    constexpr int BK = 64;
    __shared__ __align__(16) short lAs[128 * BK];
    __shared__ __align__(16) short lBs[128 * BK];
    int bid = blockIdx.x;
    int nb  = (bid & 7) * 128 + (bid >> 3);
    int tm  = nb & 7;
    int tn  = nb >> 3;
    int m0 = tm * 128, n0 = tn * 128;
    int t = threadIdx.x;
    int lane = t & 63, w = t >> 6;
    int wr = (w >> 1) * 64, wc = (w & 1) * 64;
    f32x4 acc[4][4] = {};
    float4 ra[4][2], rb[4][2];
    float  sc[4];
    int    srow[4], sgrp[4];
    #pragma unroll
    for (int i = 0; i < 4; ++i) {
        int li = t + i * 256;
        srow[i] = li >> 3;
        sgrp[i] = li & 7;
        sc[i]   = rn[m0 + srow[i]];
    }
    auto load_tiles = [&](int kt) {
        int k0 = kt * BK;
        #pragma unroll
        for (int i = 0; i < 4; ++i) {
            const float4* pa = reinterpret_cast<const float4*>(
                A + (size_t)(m0 + srow[i]) * D_K + k0 + sgrp[i] * 8);
            ra[i][0] = pa[0]; ra[i][1] = pa[1];
            const float4* pb = reinterpret_cast<const float4*>(
                Bm + (size_t)(n0 + srow[i]) * D_K + k0 + sgrp[i] * 8);
            rb[i][0] = pb[0]; rb[i][1] = pb[1];
        }
    };
    auto write_tiles = [&]() {
        #pragma unroll
        for (int i = 0; i < 4; ++i) {
            int row = srow[i];
            int slot = sgrp[i] ^ (row & 7);
            float s = sc[i];
            bf16x8 va, vb;
            va[0] = (short)f2bf(ra[i][0].x * s); va[1] = (short)f2bf(ra[i][0].y * s);
            va[2] = (short)f2bf(ra[i][0].z * s); va[3] = (short)f2bf(ra[i][0].w * s);
            va[4] = (short)f2bf(ra[i][1].x * s); va[5] = (short)f2bf(ra[i][1].y * s);
            va[6] = (short)f2bf(ra[i][1].z * s); va[7] = (short)f2bf(ra[i][1].w * s);
            vb[0] = (short)f2bf(rb[i][0].x); vb[1] = (short)f2bf(rb[i][0].y);
            vb[2] = (short)f2bf(rb[i][0].z); vb[3] = (short)f2bf(rb[i][0].w);
            vb[4] = (short)f2bf(rb[i][1].x); vb[5] = (short)f2bf(rb[i][1].y);
            vb[6] = (short)f2bf(rb[i][1].z); vb[7] = (short)f2bf(rb[i][1].w);
            *reinterpret_cast<bf16x8*>(&lAs[row * BK + slot * 8]) = va;
            *reinterpret_cast<bf16x8*>(&lBs[row * BK + slot * 8]) = vb;
        }
    };
    auto compute = [&]() {
        #pragma unroll
        for (int ks = 0; ks < 2; ++ks) {
            bf16x8 af[4], bfr[4];
            #pragma unroll
            for (int f = 0; f < 4; ++f) {
                int arow = wr + f * 16 + (lane & 15);
                int aslot = (ks * 4 + (lane >> 4)) ^ (arow & 7);
                af[f] = *reinterpret_cast<const bf16x8*>(&lAs[arow * BK + aslot * 8]);
                int brow = wc + f * 16 + (lane & 15);
                int bslot = (ks * 4 + (lane >> 4)) ^ (brow & 7);
                bfr[f] = *reinterpret_cast<const bf16x8*>(&lBs[brow * BK + bslot * 8]);
            }
            #pragma unroll
            for (int m = 0; m < 4; ++m)
                #pragma unroll
                for (int n = 0; n < 4; ++n)
                    acc[m][n] = __builtin_amdgcn_mfma_f32_16x16x32_bf16(
                        af[m], bfr[n], acc[m][n], 0, 0, 0);
        }
    };
    load_tiles(0);
    write_tiles();
    for (int kt = 1; kt < D_K / BK; ++kt) {
        __syncthreads();
        load_tiles(kt);
        compute();
        __syncthreads();
        write_tiles();
    }
    __syncthreads();
    compute();
    #pragma unroll
    for (int m = 0; m < 4; ++m) {
        int r = m0 + wr + m * 16 + (lane >> 4) * 4;
        #pragma unroll
        for (int j = 0; j < 4; ++j) {
            float* cp = C + (size_t)(r + j) * N_N + n0 + wc + (lane & 15);
            #pragma unroll
            for (int n = 0; n < 4; ++n)
                cp[n * 16] = acc[m][n][j] * TEMP_INV;
        }
    }
}

extern "C" void kernel_launch(void* const* d_in, const int* in_sizes, int n_in,
                              void* d_out, int out_size, void* d_ws, size_t ws_size,
                              hipStream_t stream) {
    const float* inputs   = (const float*)d_in[0];
    // d_in[1] = targets (unused by the forward output)
    const float* features = (const float*)d_in[2];
    float* out = (float*)d_out;

    const size_t needA = (size_t)M_M * D_K * 2;           // 4 MiB
    if (ws_size >= needA) {
        unsigned short* Abf = (unsigned short*)d_ws;
        anorm_kernel<<<M_M, 256, 0, stream>>>(inputs, Abf);
        gemm8f_kernel<<<(M_M / 256) * (N_N / 256), 512, 0, stream>>>(Abf, features, out);
    } else {
        float* rn = (float*)d_ws;   // 1024 floats
        rnorm_kernel<<<M_M, 256, 0, stream>>>(inputs, rn);
        gemm_kernel<<<(M_M / 128) * (N_N / 128), 256, 0, stream>>>(inputs, features, rn, out);
    }
}

// Round 7
// 129.326 us; speedup vs baseline: 1.0453x; 1.0453x over previous
//
#include <hip/hip_runtime.h>
#include <hip/hip_bf16.h>

// C[1024,16384] = l2norm_rows(inputs[1024,2048]) @ features[16384,2048]^T / 0.05
// Round 7: fused-B GEMM with DEPTH-2 B register prefetch (rbE/rbO).
// B(T+2) loaded at T.P1, ds_written at T+1.P4 (7-phase latency cover).
// Single wait value vmcnt(12) at P2/P4-post (ledger-verified).

typedef short bf16x8 __attribute__((ext_vector_type(8)));
typedef float f32x4  __attribute__((ext_vector_type(4)));

#define D_K   2048
#define N_N   16384
#define M_M   1024
#define TEMP_INV 20.0f

__device__ __forceinline__ unsigned short f2bf(float f) {
    unsigned u = __builtin_bit_cast(unsigned, f);
    u += 0x7FFFu + ((u >> 16) & 1u);   // round-to-nearest-even (finite data)
    return (unsigned short)(u >> 16);
}

#define GLOAD16(g, l) __builtin_amdgcn_global_load_lds(                        \
    (const __attribute__((address_space(1))) unsigned int*)(g),                \
    (__attribute__((address_space(3))) unsigned int*)(l), 16, 0, 0)

// ---------------- pass 1: row-norm + convert A -> bf16 --------------------
__global__ __launch_bounds__(256) void anorm_kernel(const float* __restrict__ x,
                                                    unsigned short* __restrict__ abf) {
    int row = blockIdx.x;
    int t = threadIdx.x;
    const float4* xr = reinterpret_cast<const float4*>(x + (size_t)row * D_K);
    float4 a = xr[t * 2];
    float4 b = xr[t * 2 + 1];
    float s = a.x*a.x + a.y*a.y + a.z*a.z + a.w*a.w
            + b.x*b.x + b.y*b.y + b.z*b.z + b.w*b.w;
    #pragma unroll
    for (int off = 32; off > 0; off >>= 1) s += __shfl_down(s, off);
    __shared__ float ps[4];
    __shared__ float sbc;
    if ((t & 63) == 0) ps[t >> 6] = s;
    __syncthreads();
    if (t == 0) {
        float tot = ps[0] + ps[1] + ps[2] + ps[3];
        sbc = 1.0f / fmaxf(sqrtf(tot), 1e-12f);
    }
    __syncthreads();
    float rs = sbc;
    bf16x8 v;
    v[0] = (short)f2bf(a.x * rs); v[1] = (short)f2bf(a.y * rs);
    v[2] = (short)f2bf(a.z * rs); v[3] = (short)f2bf(a.w * rs);
    v[4] = (short)f2bf(b.x * rs); v[5] = (short)f2bf(b.y * rs);
    v[6] = (short)f2bf(b.z * rs); v[7] = (short)f2bf(b.w * rs);
    *reinterpret_cast<bf16x8*>(abf + (size_t)row * D_K + t * 8) = v;
}

// ---------------- pass 2: 256x256 8-phase GEMM, fused B, depth-2 ----------
// 512 threads = 8 waves (2M x 4N). LDS 128 KiB = buf[2] x {A 32K, B 32K}.
// Per-tile VMEM issue: P1: B8(T+2)->rb[T&1]; P2: A2 k1(T+1); P3: A2 k0(T+2).
// Waits: vmcnt(12) at P2-post (retires B8(T+1), A-k1(T)) and P4-post
// (retires A-k0(T+1)). P4-post then ds_writes B(T+1) from rb[(T+1)&1].
// WAR audit: A-k1 staged into buf[(T+1)&1]s1 (last read T-1.P3/P4); A-k0
// into buf[T&1]s0 (last read T.P2); B write into buf[(T+1)&1] (last read
// T-1.P1/P3). RAW audit: every region retired by a vmcnt >=1 phase before
// first read; LDS write->read visibility via barrier + in-order DS pipe
// (R5/R6-verified pattern).
__global__ __launch_bounds__(512, 2) void gemm8f_kernel(const unsigned short* __restrict__ Abf,
                                                        const float* __restrict__ Bm,
                                                        float* __restrict__ C) {
    __shared__ __align__(16) unsigned short lds[65536];   // 128 KiB

    int bid = blockIdx.x;
    int wg  = (bid & 7) * 32 + (bid >> 3);     // bijective XCD swizzle (256%8==0)
    int tm  = wg & 3, tn = wg >> 2;
    int m_blk = tm * 256, n_blk = tn * 256;

    int t = threadIdx.x, lane = t & 63, w = t >> 6;
    int wm = w >> 2, wn = w & 3;                     // 2 x 4 wave grid

    // ds_read lane constants: slot = chunk ^ ((row>>1)&3)
    int l15  = lane & 15;
    int slot = ((lane >> 4) ^ ((l15 >> 1) & 3)) * 16;
    int aoff = (wm * 128 + l15) * 64 + slot;
    int boff = (wn * 64  + l15) * 64 + slot;

    // A stage source (pre-swizzled global chunk, rule #21), dest linear
    const unsigned short* gA[2];
    int sdst[2];
    #pragma unroll
    for (int pass = 0; pass < 2; ++pass) {
        int r = pass * 128 + (t >> 2);
        int csrc = (t & 3) ^ ((r >> 1) & 3);
        gA[pass] = Abf + (size_t)(m_blk + r) * D_K + csrc * 8;
        sdst[pass] = pass * 8192 + w * 1024;
    }
    auto stageA = [&](int s, int b, int ktile) {
        int kt = ktile < 32 ? ktile : 31;              // tail clamp (dead regions)
        int koff = kt * 64 + s * 32;
        int ldsb = b * 65536 + s * 16384;
        GLOAD16(gA[0] + koff, (char*)lds + ldsb + sdst[0]);
        GLOAD16(gA[1] + koff, (char*)lds + ldsb + sdst[1]);
    };

    // B reg-staging: thread owns (row = t>>1, k-half = t&1) = 32 fp32/K-tile
    int brow = t >> 1, bhalf = t & 1;
    const float* gBsrc = Bm + (size_t)(n_blk + brow) * D_K + bhalf * 32;
    unsigned wbase = (unsigned)(32768 + bhalf * 16384 + brow * 64);
    int wsw = (brow >> 1) & 3;                         // write-side XOR swizzle

    float4 rbE[8], rbO[8];                             // depth-2 B buffers

#define LOADB(rb, ktile)                                                       \
    {                                                                          \
        int kt_ = (ktile) < 32 ? (ktile) : 31;                                 \
        const float4* p_ = reinterpret_cast<const float4*>(gBsrc + kt_ * 64);  \
        _Pragma("unroll")                                                      \
        for (int g = 0; g < 8; ++g) rb[g] = p_[g];                             \
    }
#define WRITEB(rb, b)                                                          \
    {                                                                          \
        char* dst_ = (char*)lds + (b) * 65536 + wbase;                         \
        _Pragma("unroll")                                                      \
        for (int g = 0; g < 4; ++g) {                                          \
            float4 x_ = rb[g * 2], y_ = rb[g * 2 + 1];                         \
            bf16x8 v_;                                                         \
            v_[0] = (short)f2bf(x_.x); v_[1] = (short)f2bf(x_.y);              \
            v_[2] = (short)f2bf(x_.z); v_[3] = (short)f2bf(x_.w);              \
            v_[4] = (short)f2bf(y_.x); v_[5] = (short)f2bf(y_.y);              \
            v_[6] = (short)f2bf(y_.z); v_[7] = (short)f2bf(y_.w);              \
            *reinterpret_cast<bf16x8*>(dst_ + ((g ^ wsw) * 16)) = v_;          \
        }                                                                      \
    }
#define VM12 asm volatile("s_waitcnt vmcnt(12)" ::: "memory")

    f32x4 acc[8][4] = {};
    bf16x8 bfr[4];

#define PHASE(b, mh, s, LOADFRB, PRE, POST)                                    \
    {                                                                          \
        bf16x8 af[4];                                                          \
        _Pragma("unroll")                                                      \
        for (int f = 0; f < 4; ++f)                                            \
            af[f] = *reinterpret_cast<const bf16x8*>(                          \
                (char*)lds + (b) * 65536 + (s) * 16384 + aoff +                \
                ((mh) * 64 + f * 16) * 64);                                    \
        if (LOADFRB) {                                                         \
            _Pragma("unroll")                                                  \
            for (int n = 0; n < 4; ++n)                                        \
                bfr[n] = *reinterpret_cast<const bf16x8*>(                     \
                    (char*)lds + (b) * 65536 + 32768 + (s) * 16384 + boff +    \
                    n * 1024);                                                 \
        }                                                                      \
        PRE;                                                                   \
        asm volatile("s_barrier" ::: "memory");                                \
        asm volatile("s_waitcnt lgkmcnt(0)" ::: "memory");                     \
        __builtin_amdgcn_sched_barrier(0);                                     \
        __builtin_amdgcn_s_setprio(1);                                         \
        _Pragma("unroll")                                                      \
        for (int f = 0; f < 4; ++f) {                                          \
            _Pragma("unroll")                                                  \
            for (int n = 0; n < 4; ++n)                                        \
                acc[(mh) * 4 + f][n] = __builtin_amdgcn_mfma_f32_16x16x32_bf16(\
                    af[f], bfr[n], acc[(mh) * 4 + f][n], 0, 0, 0);             \
        }                                                                      \
        __builtin_amdgcn_s_setprio(0);                                         \
        POST;                                                                  \
        asm volatile("s_barrier" ::: "memory");                                \
    }

    // prologue -> steady state [B8(1), A2(k1,0), A2(k0,1)] in flight,
    // buf0 = A(0)+B(0) complete, rbO = B(1) regs.
    LOADB(rbE, 0);                                   // B8(0)
    stageA(0, 0, 0);                                 // A-k0(0) -> buf0
    asm volatile("s_waitcnt vmcnt(2)" ::: "memory"); // B8(0) landed
    WRITEB(rbE, 0);                                  // B(0) -> buf0
    LOADB(rbO, 1);                                   // B8(1)
    stageA(1, 0, 0);                                 // A-k1(0) -> buf0
    stageA(0, 1, 1);                                 // A-k0(1) -> buf1
    VM12;                                            // A-k0(0) landed
    asm volatile("s_barrier" ::: "memory");

    for (int u = 0; u < 16; ++u) {
        // K-tile T=2u (buf0)
        PHASE(0, 0, 0, true,  LOADB(rbE, 2 * u + 2),   (void)0)
        PHASE(0, 1, 0, false, stageA(1, 1, 2 * u + 1), VM12)
        PHASE(0, 0, 1, true,  stageA(0, 0, 2 * u + 2), (void)0)
        PHASE(0, 1, 1, false, (void)0,                 VM12; WRITEB(rbO, 1))
        // K-tile T=2u+1 (buf1)
        PHASE(1, 0, 0, true,  LOADB(rbO, 2 * u + 3),   (void)0)
        PHASE(1, 1, 0, false, stageA(1, 0, 2 * u + 2), VM12)
        PHASE(1, 0, 1, true,  stageA(0, 1, 2 * u + 3), (void)0)
        PHASE(1, 1, 1, false, (void)0,                 VM12; WRITEB(rbE, 0))
    }
#undef PHASE
#undef LOADB
#undef WRITEB
#undef VM12

    // epilogue: C/D layout col=lane&15, row=(lane>>4)*4+j [m89-verified]
    #pragma unroll
    for (int f = 0; f < 8; ++f) {
        int r = m_blk + wm * 128 + (f >> 2) * 64 + (f & 3) * 16 + (lane >> 4) * 4;
        #pragma unroll
        for (int j = 0; j < 4; ++j) {
            float* cp = C + (size_t)(r + j) * N_N + n_blk + wn * 64 + (lane & 15);
            #pragma unroll
            for (int n = 0; n < 4; ++n)
                cp[n * 16] = acc[f][n][j] * TEMP_INV;
        }
    }
}

// ================= fallback (round-1 fused fp32-staged kernel) ============
__global__ __launch_bounds__(256) void rnorm_kernel(const float* __restrict__ x,
                                                    float* __restrict__ rn) {
    int row = blockIdx.x;
    const float4* xr = reinterpret_cast<const float4*>(x + (size_t)row * D_K);
    int t = threadIdx.x;
    float4 a = xr[t];
    float4 b = xr[t + 256];
    float s = a.x*a.x + a.y*a.y + a.z*a.z + a.w*a.w
            + b.x*b.x + b.y*b.y + b.z*b.z + b.w*b.w;
    #pragma unroll
    for (int off = 32; off > 0; off >>= 1) s += __shfl_down(s, off);
    __shared__ float ps[4];
    int wave = t >> 6, lane = t & 63;
    if (lane == 0) ps[wave] = s;
    __syncthreads();
    if (t == 0) {
        float tot = ps[0] + ps[1] + ps[2] + ps[3];
        rn[row] = 1.0f / fmaxf(sqrtf(tot), 1e-12f);
    }
}

__global__ __launch_bounds__(256, 2) void gemm_kernel(const float* __restrict__ A,
                                                      const float* __restrict__ Bm,
                                                      const float* __restrict__ rn,
                                                      float* __restrict__ C) {
    constexpr int BK = 64;
    __shared__ __align__(16) short lAs[128 * BK];
    __shared__ __align__(16) short lBs[128 * BK];
    int bid = blockIdx.x;
    int nb  = (bid & 7) * 128 + (bid >> 3);
    int tm  = nb & 7;
    int tn  = nb >> 3;
    int m0 = tm * 128, n0 = tn * 128;
    int t = threadIdx.x;
    int lane = t & 63, w = t >> 6;
    int wr = (w >> 1) * 64, wc = (w & 1) * 64;
    f32x4 acc[4][4] = {};
    float4 ra[4][2], rb[4][2];
    float  sc[4];
    int    srow[4], sgrp[4];
    #pragma unroll
    for (int i = 0; i < 4; ++i) {
        int li = t + i * 256;
        srow[i] = li >> 3;
        sgrp[i] = li & 7;
        sc[i]   = rn[m0 + srow[i]];
    }
    auto load_tiles = [&](int kt) {
        int k0 = kt * BK;
        #pragma unroll
        for (int i = 0; i < 4; ++i) {
            const float4* pa = reinterpret_cast<const float4*>(
                A + (size_t)(m0 + srow[i]) * D_K + k0 + sgrp[i] * 8);
            ra[i][0] = pa[0]; ra[i][1] = pa[1];
            const float4* pb = reinterpret_cast<const float4*>(
                Bm + (size_t)(n0 + srow[i]) * D_K + k0 + sgrp[i] * 8);
            rb[i][0] = pb[0]; rb[i][1] = pb[1];
        }
    };
    auto write_tiles = [&]() {
        #pragma unroll
        for (int i = 0; i < 4; ++i) {
            int row = srow[i];
            int slotw = sgrp[i] ^ (row & 7);
            float s = sc[i];
            bf16x8 va, vb;
            va[0] = (short)f2bf(ra[i][0].x * s); va[1] = (short)f2bf(ra[i][0].y * s);
            va[2] = (short)f2bf(ra[i][0].z * s); va[3] = (short)f2bf(ra[i][0].w * s);
            va[4] = (short)f2bf(ra[i][1].x * s); va[5] = (short)f2bf(ra[i][1].y * s);
            va[6] = (short)f2bf(ra[i][1].z * s); va[7] = (short)f2bf(ra[i][1].w * s);
            vb[0] = (short)f2bf(rb[i][0].x); vb[1] = (short)f2bf(rb[i][0].y);
            vb[2] = (short)f2bf(rb[i][0].z); vb[3] = (short)f2bf(rb[i][0].w);
            vb[4] = (short)f2bf(rb[i][1].x); vb[5] = (short)f2bf(rb[i][1].y);
            vb[6] = (short)f2bf(rb[i][1].z); vb[7] = (short)f2bf(rb[i][1].w);
            *reinterpret_cast<bf16x8*>(&lAs[row * BK + slotw * 8]) = va;
            *reinterpret_cast<bf16x8*>(&lBs[row * BK + slotw * 8]) = vb;
        }
    };
    auto compute = [&]() {
        #pragma unroll
        for (int ks = 0; ks < 2; ++ks) {
            bf16x8 af[4], bfr[4];
            #pragma unroll
            for (int f = 0; f < 4; ++f) {
                int arow = wr + f * 16 + (lane & 15);
                int aslot = (ks * 4 + (lane >> 4)) ^ (arow & 7);
                af[f] = *reinterpret_cast<const bf16x8*>(&lAs[arow * BK + aslot * 8]);
                int brow = wc + f * 16 + (lane & 15);
                int bslot = (ks * 4 + (lane >> 4)) ^ (brow & 7);
                bfr[f] = *reinterpret_cast<const bf16x8*>(&lBs[brow * BK + bslot * 8]);
            }
            #pragma unroll
            for (int m = 0; m < 4; ++m)
                #pragma unroll
                for (int n = 0; n < 4; ++n)
                    acc[m][n] = __builtin_amdgcn_mfma_f32_16x16x32_bf16(
                        af[m], bfr[n], acc[m][n], 0, 0, 0);
        }
    };
    load_tiles(0);
    write_tiles();
    for (int kt = 1; kt < D_K / BK; ++kt) {
        __syncthreads();
        load_tiles(kt);
        compute();
        __syncthreads();
        write_tiles();
    }
    __syncthreads();
    compute();
    #pragma unroll
    for (int m = 0; m < 4; ++m) {
        int r = m0 + wr + m * 16 + (lane >> 4) * 4;
        #pragma unroll
        for (int j = 0; j < 4; ++j) {
            float* cp = C + (size_t)(r + j) * N_N + n0 + wc + (lane & 15);
            #pragma unroll
            for (int n = 0; n < 4; ++n)
                cp[n * 16] = acc[m][n][j] * TEMP_INV;
        }
    }
}

extern "C" void kernel_launch(void* const* d_in, const int* in_sizes, int n_in,
                              void* d_out, int out_size, void* d_ws, size_t ws_size,
                              hipStream_t stream) {
    const float* inputs   = (const float*)d_in[0];
    // d_in[1] = targets (unused by the forward output)
    const float* features = (const float*)d_in[2];
    float* out = (float*)d_out;

    const size_t needA = (size_t)M_M * D_K * 2;           // 4 MiB
    if (ws_size >= needA) {
        unsigned short* Abf = (unsigned short*)d_ws;
        anorm_kernel<<<M_M, 256, 0, stream>>>(inputs, Abf);
        gemm8f_kernel<<<(M_M / 256) * (N_N / 256), 512, 0, stream>>>(Abf, features, out);
    } else {
        float* rn = (float*)d_ws;   // 1024 floats
        rnorm_kernel<<<M_M, 256, 0, stream>>>(inputs, rn);
        gemm_kernel<<<(M_M / 128) * (N_N / 128), 256, 0, stream>>>(inputs, features, rn, out);
    }
}

// Round 8
// 103.778 us; speedup vs baseline: 1.3027x; 1.2462x over previous
//
#include <hip/hip_runtime.h>
#include <hip/hip_bf16.h>

// C[1024,16384] = l2norm_rows(inputs[1024,2048]) @ features[16384,2048]^T / 0.05
// Round 8: REVERT to the verified R5 pipeline (fused-B experiments R6/R7 both
// collapsed to 17% MfmaUtil). gemm8_kernel is byte-identical to R5. anorm and
// bconv are merged into one prep_kernel (fewer launches, scheduler backfill).

typedef short bf16x8 __attribute__((ext_vector_type(8)));
typedef float f32x4  __attribute__((ext_vector_type(4)));

#define D_K   2048
#define N_N   16384
#define M_M   1024
#define TEMP_INV 20.0f

__device__ __forceinline__ unsigned short f2bf(float f) {
    unsigned u = __builtin_bit_cast(unsigned, f);
    u += 0x7FFFu + ((u >> 16) & 1u);   // round-to-nearest-even (finite data)
    return (unsigned short)(u >> 16);
}

#define GLOAD16(g, l) __builtin_amdgcn_global_load_lds(                        \
    (const __attribute__((address_space(1))) unsigned int*)(g),                \
    (__attribute__((address_space(3))) unsigned int*)(l), 16, 0, 0)

// ---------------- pass 1: prep = anorm (blocks 0..1023) + bconv (rest) ----
__global__ __launch_bounds__(256) void prep_kernel(const float* __restrict__ x,
                                                   const float* __restrict__ B,
                                                   unsigned short* __restrict__ abf,
                                                   unsigned short* __restrict__ bbf) {
    int t = threadIdx.x;
    if (blockIdx.x < M_M) {
        // --- anorm: one block per row of A ---
        int row = blockIdx.x;
        const float4* xr = reinterpret_cast<const float4*>(x + (size_t)row * D_K);
        float4 a = xr[t * 2];
        float4 b = xr[t * 2 + 1];
        float s = a.x*a.x + a.y*a.y + a.z*a.z + a.w*a.w
                + b.x*b.x + b.y*b.y + b.z*b.z + b.w*b.w;
        #pragma unroll
        for (int off = 32; off > 0; off >>= 1) s += __shfl_down(s, off);
        __shared__ float ps[4];
        __shared__ float sbc;
        if ((t & 63) == 0) ps[t >> 6] = s;
        __syncthreads();
        if (t == 0) {
            float tot = ps[0] + ps[1] + ps[2] + ps[3];
            sbc = 1.0f / fmaxf(sqrtf(tot), 1e-12f);
        }
        __syncthreads();
        float rs = sbc;
        bf16x8 v;
        v[0] = (short)f2bf(a.x * rs); v[1] = (short)f2bf(a.y * rs);
        v[2] = (short)f2bf(a.z * rs); v[3] = (short)f2bf(a.w * rs);
        v[4] = (short)f2bf(b.x * rs); v[5] = (short)f2bf(b.y * rs);
        v[6] = (short)f2bf(b.z * rs); v[7] = (short)f2bf(b.w * rs);
        *reinterpret_cast<bf16x8*>(abf + (size_t)row * D_K + t * 8) = v;
    } else {
        // --- bconv: grid-stride fp32 -> bf16 over features ---
        const size_t nv = (size_t)N_N * D_K / 8;     // 8 elements per step
        size_t stride = (size_t)(gridDim.x - M_M) * blockDim.x;
        for (size_t v = (size_t)(blockIdx.x - M_M) * blockDim.x + t; v < nv; v += stride) {
            const float4* p = reinterpret_cast<const float4*>(B) + v * 2;
            float4 a = p[0], b = p[1];
            bf16x8 o;
            o[0] = (short)f2bf(a.x); o[1] = (short)f2bf(a.y);
            o[2] = (short)f2bf(a.z); o[3] = (short)f2bf(a.w);
            o[4] = (short)f2bf(b.x); o[5] = (short)f2bf(b.y);
            o[6] = (short)f2bf(b.z); o[7] = (short)f2bf(b.w);
            reinterpret_cast<bf16x8*>(bbf)[v] = o;
        }
    }
}

// ---------------- pass 2: 256x256 8-phase GEMM (R5-verified, unchanged) ---
// 512 threads = 8 waves (2M x 4N). LDS 128 KiB = buf[2] x {A 32K, B 32K},
// region (mat, kstep) = 256 rows x 32 cols bf16 = 16 KB = one half-tile.
// Per phase: ds_read frags + stage 1 half-tile -> s_barrier -> lgkmcnt(0) ->
// setprio(1) 16 MFMA setprio(0) -> [vmcnt(8) at p2,p4] -> s_barrier.
// Stage slots during K-tile t: p1/p2 -> k1 of t+1 (buf[(t+1)&1]),
// p3/p4 -> k0 of t+2 (buf[t&1], regions last read at p2). vmcnt(8) keeps
// 4 half-tiles in flight; K-index clamped at tail for uniform counting.
__global__ __launch_bounds__(512, 2) void gemm8_kernel(const unsigned short* __restrict__ Abf,
                                                       const unsigned short* __restrict__ Bbf,
                                                       float* __restrict__ C) {
    __shared__ __align__(16) unsigned short lds[65536];   // 128 KiB

    // 256 wgs = 4 Mtiles x 64 Ntiles; bijective XCD swizzle (256 % 8 == 0).
    int bid = blockIdx.x;
    int wg  = (bid & 7) * 32 + (bid >> 3);
    int tm  = wg & 3, tn = wg >> 2;
    int m_blk = tm * 256, n_blk = tn * 256;

    int t = threadIdx.x, lane = t & 63, w = t >> 6;
    int wm = w >> 2, wn = w & 3;                     // 2 x 4 wave grid

    // ds_read lane constants: slot = chunk ^ ((row>>1)&3), row bits 1-2 from lane&15
    int l15  = lane & 15;
    int slot = ((lane >> 4) ^ ((l15 >> 1) & 3)) * 16;     // byte slot offset
    int aoff = (wm * 128 + l15) * 64 + slot;              // A region byte off
    int boff = (wn * 64  + l15) * 64 + slot;              // B region byte off

    // stage source pointers (pre-swizzled global chunk per rule #21)
    const unsigned short* gA[2];
    const unsigned short* gB[2];
    int sdst[2];
    #pragma unroll
    for (int pass = 0; pass < 2; ++pass) {
        int r = pass * 128 + (t >> 2);
        int csrc = (t & 3) ^ ((r >> 1) & 3);
        gA[pass] = Abf + (size_t)(m_blk + r) * D_K + csrc * 8;
        gB[pass] = Bbf + (size_t)(n_blk + r) * D_K + csrc * 8;
        sdst[pass] = pass * 8192 + w * 1024;   // wave-uniform LDS dest base
    }

    // stage one half-tile: region (mat, s) of K-tile kt into buffer b
    auto stage = [&](int mat, int s, int b, int ktile) {
        int kt = ktile < 32 ? ktile : 31;              // tail clamp (safe: dead regions)
        int koff = kt * 64 + s * 32;
        int ldsb = b * 65536 + mat * 32768 + s * 16384;
        GLOAD16((mat ? gB[0] : gA[0]) + koff, (char*)lds + ldsb + sdst[0]);
        GLOAD16((mat ? gB[1] : gA[1]) + koff, (char*)lds + ldsb + sdst[1]);
    };

    f32x4 acc[8][4] = {};
    bf16x8 bfr[4];                                     // persists across phase pairs

#define PHASE(b, mh, s, LOADB, stMat, stS, stB, stKt, VM)                      \
    {                                                                          \
        bf16x8 af[4];                                                          \
        _Pragma("unroll")                                                      \
        for (int f = 0; f < 4; ++f)                                            \
            af[f] = *reinterpret_cast<const bf16x8*>(                          \
                (char*)lds + (b) * 65536 + (s) * 16384 + aoff +                \
                ((mh) * 64 + f * 16) * 64);                                    \
        if (LOADB) {                                                           \
            _Pragma("unroll")                                                  \
            for (int n = 0; n < 4; ++n)                                        \
                bfr[n] = *reinterpret_cast<const bf16x8*>(                     \
                    (char*)lds + (b) * 65536 + 32768 + (s) * 16384 + boff +    \
                    n * 1024);                                                 \
        }                                                                      \
        stage(stMat, stS, stB, stKt);                                          \
        asm volatile("s_barrier" ::: "memory");                                \
        asm volatile("s_waitcnt lgkmcnt(0)" ::: "memory");                     \
        __builtin_amdgcn_sched_barrier(0);                                     \
        __builtin_amdgcn_s_setprio(1);                                         \
        _Pragma("unroll")                                                      \
        for (int f = 0; f < 4; ++f) {                                          \
            _Pragma("unroll")                                                  \
            for (int n = 0; n < 4; ++n)                                        \
                acc[(mh) * 4 + f][n] = __builtin_amdgcn_mfma_f32_16x16x32_bf16(\
                    af[f], bfr[n], acc[(mh) * 4 + f][n], 0, 0, 0);             \
        }                                                                      \
        __builtin_amdgcn_s_setprio(0);                                         \
        if (VM) asm volatile("s_waitcnt vmcnt(8)" ::: "memory");               \
        asm volatile("s_barrier" ::: "memory");                                \
    }

    // prologue: K0 full + K1 k0-halves; vmcnt(8) -> oldest 4 ops (K0 k0) landed
    stage(0, 0, 0, 0);   // A-k0(0) -> buf0
    stage(1, 0, 0, 0);   // B-k0(0)
    stage(0, 1, 0, 0);   // A-k1(0)
    stage(1, 1, 0, 0);   // B-k1(0)
    stage(0, 0, 1, 1);   // A-k0(1) -> buf1
    stage(1, 0, 1, 1);   // B-k0(1)
    asm volatile("s_waitcnt vmcnt(8)" ::: "memory");
    asm volatile("s_barrier" ::: "memory");

    for (int u = 0; u < 16; ++u) {
        int t1 = 2 * u + 1;
        // K-tile 2u (buf0)
        PHASE(0, 0, 0, true,  0, 1, 1, t1,     false)   // stage A-k1(t1)->buf1
        PHASE(0, 1, 0, false, 1, 1, 1, t1,     true )   // stage B-k1(t1)->buf1
        PHASE(0, 0, 1, true,  0, 0, 0, t1 + 1, false)   // stage A-k0(t1+1)->buf0
        PHASE(0, 1, 1, false, 1, 0, 0, t1 + 1, true )   // stage B-k0(t1+1)->buf0
        // K-tile 2u+1 (buf1)
        PHASE(1, 0, 0, true,  0, 1, 0, t1 + 1, false)   // stage A-k1(t1+1)->buf0
        PHASE(1, 1, 0, false, 1, 1, 0, t1 + 1, true )   // stage B-k1(t1+1)->buf0
        PHASE(1, 0, 1, true,  0, 0, 1, t1 + 2, false)   // stage A-k0(t1+2)->buf1
        PHASE(1, 1, 1, false, 1, 0, 1, t1 + 2, true )   // stage B-k0(t1+2)->buf1
    }
#undef PHASE

    // epilogue: C/D layout col=lane&15, row=(lane>>4)*4+j [m89-verified]
    #pragma unroll
    for (int f = 0; f < 8; ++f) {
        int r = m_blk + wm * 128 + (f >> 2) * 64 + (f & 3) * 16 + (lane >> 4) * 4;
        #pragma unroll
        for (int j = 0; j < 4; ++j) {
            float* cp = C + (size_t)(r + j) * N_N + n_blk + wn * 64 + (lane & 15);
            #pragma unroll
            for (int n = 0; n < 4; ++n)
                cp[n * 16] = acc[f][n][j] * TEMP_INV;
        }
    }
}

// ================= fallback (round-1 fused fp32-staged kernel) ============
__global__ __launch_bounds__(256) void rnorm_kernel(const float* __restrict__ x,
                                                    float* __restrict__ rn) {
    int row = blockIdx.x;
    const float4* xr = reinterpret_cast<const float4*>(x + (size_t)row * D_K);
    int t = threadIdx.x;
    float4 a = xr[t];
    float4 b = xr[t + 256];
    float s = a.x*a.x + a.y*a.y + a.z*a.z + a.w*a.w
            + b.x*b.x + b.y*b.y + b.z*b.z + b.w*b.w;
    #pragma unroll
    for (int off = 32; off > 0; off >>= 1) s += __shfl_down(s, off);
    __shared__ float ps[4];
    int wave = t >> 6, lane = t & 63;
    if (lane == 0) ps[wave] = s;
    __syncthreads();
    if (t == 0) {
        float tot = ps[0] + ps[1] + ps[2] + ps[3];
        rn[row] = 1.0f / fmaxf(sqrtf(tot), 1e-12f);
    }
}

__global__ __launch_bounds__(256, 2) void gemm_kernel(const float* __restrict__ A,
                                                      const float* __restrict__ Bm,
                                                      const float* __restrict__ rn,
                                                      float* __restrict__ C) {
    constexpr int BK = 64;
    __shared__ __align__(16) short lAs[128 * BK];
    __shared__ __align__(16) short lBs[128 * BK];
    int bid = blockIdx.x;
    int nb  = (bid & 7) * 128 + (bid >> 3);
    int tm  = nb & 7;
    int tn  = nb >> 3;
    int m0 = tm * 128, n0 = tn * 128;
    int t = threadIdx.x;
    int lane = t & 63, w = t >> 6;
    int wr = (w >> 1) * 64, wc = (w & 1) * 64;
    f32x4 acc[4][4] = {};
    float4 ra[4][2], rb[4][2];
    float  sc[4];
    int    srow[4], sgrp[4];
    #pragma unroll
    for (int i = 0; i < 4; ++i) {
        int li = t + i * 256;
        srow[i] = li >> 3;
        sgrp[i] = li & 7;
        sc[i]   = rn[m0 + srow[i]];
    }
    auto load_tiles = [&](int kt) {
        int k0 = kt * BK;
        #pragma unroll
        for (int i = 0; i < 4; ++i) {
            const float4* pa = reinterpret_cast<const float4*>(
                A + (size_t)(m0 + srow[i]) * D_K + k0 + sgrp[i] * 8);
            ra[i][0] = pa[0]; ra[i][1] = pa[1];
            const float4* pb = reinterpret_cast<const float4*>(
                Bm + (size_t)(n0 + srow[i]) * D_K + k0 + sgrp[i] * 8);
            rb[i][0] = pb[0]; rb[i][1] = pb[1];
        }
    };
    auto write_tiles = [&]() {
        #pragma unroll
        for (int i = 0; i < 4; ++i) {
            int row = srow[i];
            int slotw = sgrp[i] ^ (row & 7);
            float s = sc[i];
            bf16x8 va, vb;
            va[0] = (short)f2bf(ra[i][0].x * s); va[1] = (short)f2bf(ra[i][0].y * s);
            va[2] = (short)f2bf(ra[i][0].z * s); va[3] = (short)f2bf(ra[i][0].w * s);
            va[4] = (short)f2bf(ra[i][1].x * s); va[5] = (short)f2bf(ra[i][1].y * s);
            va[6] = (short)f2bf(ra[i][1].z * s); va[7] = (short)f2bf(ra[i][1].w * s);
        vb[0] = (short)f2bf(rb[i][0].x); vb[1] = (short)f2bf(rb[i][0].y);
        vb[2] = (short)f2bf(rb[i][0].z); vb[3] = (short)f2bf(rb[i][0].w);
        vb[4] = (short)f2bf(rb[i][1].x); vb[5] = (short)f2bf(rb[i][1].y);
        vb[6] = (short)f2bf(rb[i][1].z); vb[7] = (short)f2bf(rb[i][1].w);
            *reinterpret_cast<bf16x8*>(&lAs[row * BK + slotw * 8]) = va;
            *reinterpret_cast<bf16x8*>(&lBs[row * BK + slotw * 8]) = vb;
        }
    };
    auto compute = [&]() {
        #pragma unroll
        for (int ks = 0; ks < 2; ++ks) {
            bf16x8 af[4], bfr[4];
            #pragma unroll
            for (int f = 0; f < 4; ++f) {
                int arow = wr + f * 16 + (lane & 15);
                int aslot = (ks * 4 + (lane >> 4)) ^ (arow & 7);
                af[f] = *reinterpret_cast<const bf16x8*>(&lAs[arow * BK + aslot * 8]);
                int brow = wc + f * 16 + (lane & 15);
                int bslot = (ks * 4 + (lane >> 4)) ^ (brow & 7);
                bfr[f] = *reinterpret_cast<const bf16x8*>(&lBs[brow * BK + bslot * 8]);
            }
            #pragma unroll
            for (int m = 0; m < 4; ++m)
                #pragma unroll
                for (int n = 0; n < 4; ++n)
                    acc[m][n] = __builtin_amdgcn_mfma_f32_16x16x32_bf16(
                        af[m], bfr[n], acc[m][n], 0, 0, 0);
        }
    };
    load_tiles(0);
    write_tiles();
    for (int kt = 1; kt < D_K / BK; ++kt) {
        __syncthreads();
        load_tiles(kt);
        compute();
        __syncthreads();
        write_tiles();
    }
    __syncthreads();
    compute();
    #pragma unroll
    for (int m = 0; m < 4; ++m) {
        int r = m0 + wr + m * 16 + (lane >> 4) * 4;
        #pragma unroll
        for (int j = 0; j < 4; ++j) {
            float* cp = C + (size_t)(r + j) * N_N + n0 + wc + (lane & 15);
            #pragma unroll
            for (int n = 0; n < 4; ++n)
                cp[n * 16] = acc[m][n][j] * TEMP_INV;
        }
    }
}

extern "C" void kernel_launch(void* const* d_in, const int* in_sizes, int n_in,
                              void* d_out, int out_size, void* d_ws, size_t ws_size,
                              hipStream_t stream) {
    const float* inputs   = (const float*)d_in[0];
    // d_in[1] = targets (unused by the forward output)
    const float* features = (const float*)d_in[2];
    float* out = (float*)d_out;

    const size_t needA = (size_t)M_M * D_K * 2;           // 4 MiB
    const size_t needB = (size_t)N_N * D_K * 2;           // 64 MiB
    if (ws_size >= needA + needB) {
        unsigned short* Abf = (unsigned short*)d_ws;
        unsigned short* Bbf = Abf + (size_t)M_M * D_K;
        prep_kernel<<<M_M + 2048, 256, 0, stream>>>(inputs, features, Abf, Bbf);
        gemm8_kernel<<<(M_M / 256) * (N_N / 256), 512, 0, stream>>>(Abf, Bbf, out);
    } else {
        float* rn = (float*)d_ws;   // 1024 floats
        rnorm_kernel<<<M_M, 256, 0, stream>>>(inputs, rn);
        gemm_kernel<<<(M_M / 128) * (N_N / 128), 256, 0, stream>>>(inputs, features, rn, out);
    }
}